// Round 7
// baseline (238.368 us; speedup 1.0000x reference)
//
#include <hip/hip_runtime.h>

typedef unsigned short ushort_t;
typedef __attribute__((ext_vector_type(8))) short short8;
typedef __attribute__((ext_vector_type(4))) float floatx4;

#define TWO_PI 6.28318530717958647692f

__device__ __forceinline__ float bf2f(ushort_t u) {
  union { unsigned u; float f; } v; v.u = ((unsigned)u) << 16; return v.f;
}
__device__ __forceinline__ ushort_t f2bf(float f) {
  union { float f; unsigned u; } v; v.f = f;
  unsigned r = v.u + 0x7FFFu + ((v.u >> 16) & 1u);
  return (ushort_t)(r >> 16);
}
__device__ __forceinline__ unsigned pk(float a, float b) {
  return (unsigned)f2bf(a) | ((unsigned)f2bf(b) << 16);
}
__device__ __forceinline__ float ldin(const void* p, int idx, bool bf) {
  return bf ? bf2f(((const ushort_t*)p)[idx]) : ((const float*)p)[idx];
}
__device__ __forceinline__ bool detect_bf16(const void* xv) {
  const ushort_t* us = (const ushort_t*)xv;
  unsigned u = us[threadIdx.x & 63];
  int e = (u >> 7) & 0xFF;
  bool good = (e >= 110) && (e <= 133);
  unsigned long long m = __ballot(good);
  return __builtin_popcountll(m) >= 52;
}
__device__ __forceinline__ uint4 pack8f(const float* p) {
  float4 a = *(const float4*)p, b = *(const float4*)(p + 4);
  uint4 r;
  r.x = pk(a.x, a.y); r.y = pk(a.z, a.w);
  r.z = pk(b.x, b.y); r.w = pk(b.z, b.w);
  return r;
}

// ---------------------------------------------------------------------------
// Wconv: conv_w -> bf16 copy in ws.
// ---------------------------------------------------------------------------
__global__ __launch_bounds__(256) void paiconv_wconv(
    const void* __restrict__ xprobe, const void* __restrict__ W,
    ushort_t* __restrict__ Wc)
{
  const bool bfm = detect_bf16(xprobe);
  int i = (blockIdx.x * 256 + threadIdx.x) << 3;
  if (bfm) *(uint4*)(Wc + i) = *(const uint4*)((const ushort_t*)W + i);
  else     *(uint4*)(Wc + i) = pack8f((const float*)W + i);
}

// ---------------------------------------------------------------------------
// featT: feat[8][64][2048] -> Ft[b*2048+n][64] bf16 (128B contiguous rows).
// ---------------------------------------------------------------------------
__global__ __launch_bounds__(256) void paiconv_featT(
    const void* __restrict__ xprobe, const void* __restrict__ feat,
    ushort_t* __restrict__ Ft)
{
  const bool bfm = detect_bf16(xprobe);
  const int t = threadIdx.x;
  const int bb = blockIdx.x >> 5;
  const int n0 = (blockIdx.x & 31) << 6;
  __shared__ ushort_t tile[64 * 72];
  {
    const int c = t & 63, ng = t >> 6;
    size_t base = (((size_t)(bb * 64 + c)) << 11) + n0 + (ng << 4);
    ushort_t v[16];
    if (bfm) {
      const ushort_t* fp_ = (const ushort_t*)feat + base;
      uint4 a = *(const uint4*)fp_, b2 = *(const uint4*)(fp_ + 8);
      unsigned uu[8] = {a.x, a.y, a.z, a.w, b2.x, b2.y, b2.z, b2.w};
#pragma unroll
      for (int e = 0; e < 8; ++e) {
        v[2 * e] = (ushort_t)(uu[e] & 0xffff);
        v[2 * e + 1] = (ushort_t)(uu[e] >> 16);
      }
    } else {
      const float* fp_ = (const float*)feat + base;
#pragma unroll
      for (int k = 0; k < 16; ++k) v[k] = f2bf(fp_[k]);
    }
#pragma unroll
    for (int k = 0; k < 16; ++k) tile[(ng * 16 + k) * 72 + c] = v[k];
  }
  __syncthreads();
  {
    const int nn = t >> 2, qtr = t & 3;
    uint4 w0 = *(const uint4*)(tile + nn * 72 + qtr * 16);
    uint4 w1 = *(const uint4*)(tile + nn * 72 + qtr * 16 + 8);
    ushort_t* dst = Ft + (((size_t)(bb * 2048 + n0 + nn)) << 6) + (qtr << 4);
    *(uint4*)dst = w0;
    *(uint4*)(dst + 8) = w1;
  }
}

// ---------------------------------------------------------------------------
// Phase 1: 2 points/block. MFMA for mlp and feats@perm. A[p][4096] bf16.
// (unchanged from round 6 — verified)
// ---------------------------------------------------------------------------
__global__ __launch_bounds__(256) void paiconv_phase1(
    const void* __restrict__ x,       // [8,3,2048]
    const ushort_t* __restrict__ Ft,  // [16384][64] bf16
    const int*  __restrict__ nbr,     // [8,2048,32]
    const void* __restrict__ Brff,    // [7,32]
    const void* __restrict__ kern,    // [3,32]
    const void* __restrict__ mlpw,    // [64,64]
    const void* __restrict__ mlpb,    // [64]
    ushort_t*   __restrict__ Ag)      // [16384,4096] bf16
{
  const bool bfm = detect_bf16(x);
  const int t = threadIdx.x;
  const int p0 = blockIdx.x << 1;
  const int b  = p0 >> 11;
  const int w = t >> 6, lane = t & 63, lrow = lane & 15, quad = lane >> 4;

  __shared__ ushort_t sRt[64 * 72];
  __shared__ ushort_t sF[2 * 128 * 40];
  __shared__ ushort_t sU[64 * 72];
  __shared__ float sRel[2][32][3];
  __shared__ float sDis[2][32];
  __shared__ float sRep[2][3];
  __shared__ float sBr[224];
  __shared__ float sKn[96];
  __shared__ float sMb[64];

  const int gpt = t >> 7, gj = (t >> 2) & 31, gch = t & 3;
  const int gidx = nbr[((p0 + gpt) << 5) + gj];
  const ushort_t* gfr = Ft + (((size_t)(b * 2048 + gidx)) << 6) + (gch << 4);
  uint4 g0 = ((const uint4*)gfr)[0];
  uint4 g1 = ((const uint4*)gfr)[1];

  if (t < 224) sBr[t] = ldin(Brff, t, bfm);
  if (t < 96)  sKn[t] = ldin(kern, t, bfm);
  if (t < 64)  sMb[t] = ldin(mlpb, t, bfm);
  {
    int c = t >> 2, q0 = (t & 3) << 4;
    uint4 w0, w1;
    if (bfm) {
      const ushort_t* mp = (const ushort_t*)mlpw + c * 64 + q0;
      w0 = *(const uint4*)mp; w1 = *(const uint4*)(mp + 8);
    } else {
      const float* mp = (const float*)mlpw + c * 64 + q0;
      w0 = pack8f(mp); w1 = pack8f(mp + 8);
    }
    *(uint4*)(sU + c * 72 + q0) = w0;
    *(uint4*)(sU + c * 72 + q0 + 8) = w1;
  }
  if (t < 64) {
    int pt = t >> 5, i = t & 31;
    int p = p0 + pt;
    int idx  = nbr[(p << 5) + i];
    int idx0 = nbr[(p << 5)];
    int xo = b * 6144;
    float rx = ldin(x, xo + idx0, bfm);
    float ry = ldin(x, xo + 2048 + idx0, bfm);
    float rz = ldin(x, xo + 4096 + idx0, bfm);
    float cx = ldin(x, xo + idx, bfm);
    float cy = ldin(x, xo + 2048 + idx, bfm);
    float cz = ldin(x, xo + 4096 + idx, bfm);
    float dx = cx - rx, dy = cy - ry, dz = cz - rz;
    sRel[pt][i][0] = dx; sRel[pt][i][1] = dy; sRel[pt][i][2] = dz;
    sDis[pt][i] = sqrtf(dx * dx + dy * dy + dz * dz);
    if (i == 0) { sRep[pt][0] = rx; sRep[pt][1] = ry; sRep[pt][2] = rz; }
  }
  __syncthreads();   // b1

  {
    int jn = t >> 2, mh = (t & 3) << 3;
    int pt = jn >> 5, j = jn & 31;
    float pos[7];
    pos[0] = TWO_PI * sRep[pt][0]; pos[1] = TWO_PI * sRep[pt][1];
    pos[2] = TWO_PI * sRep[pt][2];
    pos[3] = TWO_PI * sRel[pt][j][0]; pos[4] = TWO_PI * sRel[pt][j][1];
    pos[5] = TWO_PI * sRel[pt][j][2];
    pos[6] = TWO_PI * sDis[pt][j];
    unsigned sw[4], cw[4];
#pragma unroll
    for (int mm = 0; mm < 8; mm += 2) {
      float a0 = 0.f, a1 = 0.f;
#pragma unroll
      for (int d = 0; d < 7; ++d) {
        a0 += pos[d] * sBr[d * 32 + mh + mm];
        a1 += pos[d] * sBr[d * 32 + mh + mm + 1];
      }
      sw[mm >> 1] = pk(__sinf(a0), __sinf(a1));
      cw[mm >> 1] = pk(__cosf(a0), __cosf(a1));
    }
    ushort_t* rb = sRt + jn * 72;
    *(uint4*)(rb + mh)      = make_uint4(sw[0], sw[1], sw[2], sw[3]);
    *(uint4*)(rb + 32 + mh) = make_uint4(cw[0], cw[1], cw[2], cw[3]);
  }
  __syncthreads();   // b2

  {
    int c = (w << 4) + lrow;
    int row = (c & 31) * 4 + 2 + (c >> 5);
    float bv = sMb[c];
    short8 b0 = *(const short8*)(sU + c * 72 + (quad << 3));
    short8 b1 = *(const short8*)(sU + c * 72 + 32 + (quad << 3));
#pragma unroll
    for (int mt = 0; mt < 4; ++mt) {
      const ushort_t* rp = sRt + (mt * 16 + lrow) * 72 + (quad << 3);
      short8 a0 = *(const short8*)rp;
      short8 a1 = *(const short8*)(rp + 32);
      floatx4 acc = {0.f, 0.f, 0.f, 0.f};
      acc = __builtin_amdgcn_mfma_f32_16x16x32_bf16(a0, b0, acc, 0, 0, 0);
      acc = __builtin_amdgcn_mfma_f32_16x16x32_bf16(a1, b1, acc, 0, 0, 0);
      int pt = mt >> 1;
      int j0 = ((mt & 1) << 4) + (quad << 2);
      *(uint2*)(sF + pt * 5120 + row * 40 + j0) =
          make_uint2(pk(acc[0] + bv, acc[1] + bv), pk(acc[2] + bv, acc[3] + bv));
    }
  }
  {
    ushort_t* fp_ = sF + gpt * 5120 + (gch >> 1) * 40 + (gch & 1) * 2560 + gj;
    unsigned uu[8] = {g0.x, g0.y, g0.z, g0.w, g1.x, g1.y, g1.z, g1.w};
#pragma unroll
    for (int u = 0; u < 8; ++u) {
      fp_[(2 * u) * 160]     = (ushort_t)(uu[u] & 0xffff);
      fp_[(2 * u + 1) * 160] = (ushort_t)(uu[u] >> 16);
    }
  }
  __syncthreads();   // b3

  if (t < 64) {
    int pt = t >> 5, j = t & 31;
    float k0 = sKn[j], k1 = sKn[32 + j], k2 = sKn[64 + j];
    float col[32];
    float s1 = 0.f;
#pragma unroll
    for (int i = 0; i < 32; ++i) {
      float v = sRel[pt][i][0] * k0 + sRel[pt][i][1] * k1 + sRel[pt][i][2] * k2;
      if (i == 0 && j == 0) v += 1.0f;
      v = fmaxf(v, 0.f);
      col[i] = v; s1 += v;
    }
    float inv1 = 1.0f / (s1 + 1e-6f);
    float s2 = 0.f;
#pragma unroll
    for (int i = 0; i < 32; ++i) { float v = col[i] * inv1; v = v * v; col[i] = v; s2 += v; }
    float inv2 = 1.0f / (s2 + 1e-6f);
    unsigned pw[16];
#pragma unroll
    for (int i = 0; i < 32; i += 2) {
      float v0 = col[i] * inv2;     v0 = (v0 > 0.1f) ? v0 : 0.f;
      float v1 = col[i + 1] * inv2; v1 = (v1 > 0.1f) ? v1 : 0.f;
      pw[i >> 1] = pk(v0, v1);
    }
    ushort_t* dst = sU + pt * 1280 + j * 40;
#pragma unroll
    for (int g = 0; g < 4; ++g)
      *(uint4*)(dst + g * 8) = make_uint4(pw[4 * g], pw[4 * g + 1], pw[4 * g + 2], pw[4 * g + 3]);
  }
  __syncthreads();   // b4

  {
#pragma unroll
    for (int pt = 0; pt < 2; ++pt) {
      const ushort_t* Pp = sU + pt * 1280;
      short8 a0 = *(const short8*)(Pp + lrow * 40 + (quad << 3));
      short8 a1 = *(const short8*)(Pp + (16 + lrow) * 40 + (quad << 3));
      size_t prow = ((size_t)(p0 + pt)) << 12;
#pragma unroll
      for (int nt = 0; nt < 2; ++nt) {
        int cidx = ((w * 2 + nt) << 4) + lrow;
        short8 bfg = *(const short8*)(sF + pt * 5120 + cidx * 40 + (quad << 3));
        floatx4 z = {0.f, 0.f, 0.f, 0.f};
        floatx4 c0 = __builtin_amdgcn_mfma_f32_16x16x32_bf16(a0, bfg, z, 0, 0, 0);
        floatx4 c1 = __builtin_amdgcn_mfma_f32_16x16x32_bf16(a1, bfg, z, 0, 0, 0);
        ushort_t* ad = Ag + prow + cidx * 32 + (quad << 2);
        *(uint2*)ad        = make_uint2(pk(c0[0], c0[1]), pk(c0[2], c0[3]));
        *(uint2*)(ad + 16) = make_uint2(pk(c1[0], c1[1]), pk(c1[2], c1[3]));
      }
    }
  }
}

// ---------------------------------------------------------------------------
// Phase 2: barrier-free direct-fragment GEMM (fat-GEMV style).
// Wave tile 32x128; block = 4 waves (BM=128); split-K=2; grid (128,2).
// A-frags and W-frags loaded global->VGPR directly (no LDS, no syncthreads).
// W (1 MB) is L1/L2-resident; A streams once from HBM.
// ---------------------------------------------------------------------------
__global__ __launch_bounds__(256, 1) void paiconv_gemm(
    const ushort_t* __restrict__ A,    // [16384,4096] bf16
    const ushort_t* __restrict__ Wc,   // [128,4096] bf16
    float* __restrict__ part)          // [2][16384][128] fp32
{
  const int t = threadIdx.x;
  const int w = t >> 6, lane = t & 63, lrow = lane & 15, quad = lane >> 4;
  const int m0 = (blockIdx.x << 7) + (w << 5);   // wave rows m0..m0+32
  const int K0 = blockIdx.y << 11;               // split-K: K=2048 each

  const ushort_t* Ap0 = A + (size_t)(m0 + lrow) * 4096 + K0 + (quad << 3);
  const ushort_t* Ap1 = Ap0 + (size_t)16 * 4096;
  const ushort_t* Wp  = Wc + (size_t)lrow * 4096 + K0 + (quad << 3);

  floatx4 acc[2][8];
#pragma unroll
  for (int i = 0; i < 2; ++i)
#pragma unroll
    for (int j = 0; j < 8; ++j) acc[i][j] = (floatx4){0.f, 0.f, 0.f, 0.f};

#pragma unroll 4
  for (int ks = 0; ks < 64; ++ks) {
    const int k0 = ks << 5;
    short8 a0 = *(const short8*)(Ap0 + k0);
    short8 a1 = *(const short8*)(Ap1 + k0);
#pragma unroll
    for (int ni = 0; ni < 8; ++ni) {
      short8 bf = *(const short8*)(Wp + (size_t)(ni << 4) * 4096 + k0);
      acc[0][ni] = __builtin_amdgcn_mfma_f32_16x16x32_bf16(a0, bf, acc[0][ni], 0, 0, 0);
      acc[1][ni] = __builtin_amdgcn_mfma_f32_16x16x32_bf16(a1, bf, acc[1][ni], 0, 0, 0);
    }
  }

  float* dst = part + ((size_t)blockIdx.y << 21);
#pragma unroll
  for (int mi = 0; mi < 2; ++mi)
#pragma unroll
    for (int ni = 0; ni < 8; ++ni)
#pragma unroll
      for (int r = 0; r < 4; ++r) {
        int m = m0 + (mi << 4) + (quad << 2) + r;
        int n = (ni << 4) + lrow;
        dst[(size_t)m * 128 + n] = acc[mi][ni][r];
      }
}

// ---------------------------------------------------------------------------
// Reduce: sum 2 split-K partials + bias, transpose to out[B,C,N].
// ---------------------------------------------------------------------------
__global__ __launch_bounds__(256) void paiconv_reduce(
    const void* __restrict__ xprobe, const float* __restrict__ part,
    const void* __restrict__ bias, void* __restrict__ out)
{
  const bool bfm = detect_bf16(xprobe);
  __shared__ float buf[128 * 65];
  const int m0 = blockIdx.x << 6;
  const int b = m0 >> 11, n0 = m0 & 2047;
  const int t = threadIdx.x;

#pragma unroll 4
  for (int i = 0; i < 32; ++i) {
    int idx = i * 256 + t;
    int mt = idx >> 7, c = idx & 127;
    size_t o = (size_t)(m0 + mt) * 128 + c;
    float s = ldin(bias, c, bfm) + part[o] + part[(1u << 21) + o];
    buf[c * 65 + mt] = s;
  }
  __syncthreads();
#pragma unroll 4
  for (int i = 0; i < 32; ++i) {
    int idx = i * 256 + t;
    int c = idx >> 6, nl = idx & 63;
    float v = buf[c * 65 + nl];
    size_t o = (size_t)b * 262144 + (size_t)c * 2048 + n0 + nl;
    if (bfm) ((ushort_t*)out)[o] = f2bf(v);
    else     ((float*)out)[o] = v;
  }
}

extern "C" void kernel_launch(void* const* d_in, const int* in_sizes, int n_in,
                              void* d_out, int out_size, void* d_ws, size_t ws_size,
                              hipStream_t stream) {
  const void* x     = d_in[0];
  const void* feat  = d_in[1];
  const int*  nbr   = (const int*)d_in[2];
  const void* Brff  = d_in[3];
  const void* kern  = d_in[4];
  const void* mlpw  = d_in[5];
  const void* mlpb  = d_in[6];
  const void* convw = d_in[7];
  const void* convb = d_in[8];

  char* ws = (char*)d_ws;
  ushort_t* A   = (ushort_t*)ws;                          // 128 MiB
  ushort_t* Wcv = (ushort_t*)(ws + (size_t)134217728);    // 1 MiB
  float*    prt = (float*)(ws + (size_t)135266304);       // 16 MiB
  ushort_t* Ft  = (ushort_t*)(ws + (size_t)152043520);    // 2 MiB

  paiconv_wconv<<<256, 256, 0, stream>>>(x, convw, Wcv);
  paiconv_featT<<<256, 256, 0, stream>>>(x, feat, Ft);
  paiconv_phase1<<<8192, 256, 0, stream>>>(x, Ft, nbr, Brff, kern, mlpw, mlpb, A);
  paiconv_gemm<<<dim3(128, 2, 1), 256, 0, stream>>>(A, Wcv, prt);
  paiconv_reduce<<<256, 256, 0, stream>>>(x, prt, convb, d_out);
}

// Round 8
// 191.403 us; speedup vs baseline: 1.2454x; 1.2454x over previous
//
#include <hip/hip_runtime.h>

typedef unsigned short ushort_t;
typedef __attribute__((ext_vector_type(8))) short short8;
typedef __attribute__((ext_vector_type(4))) float floatx4;

#define TWO_PI 6.28318530717958647692f

__device__ __forceinline__ float bf2f(ushort_t u) {
  union { unsigned u; float f; } v; v.u = ((unsigned)u) << 16; return v.f;
}
__device__ __forceinline__ ushort_t f2bf(float f) {
  union { float f; unsigned u; } v; v.f = f;
  unsigned r = v.u + 0x7FFFu + ((v.u >> 16) & 1u);
  return (ushort_t)(r >> 16);
}
__device__ __forceinline__ unsigned pk(float a, float b) {
  return (unsigned)f2bf(a) | ((unsigned)f2bf(b) << 16);
}
__device__ __forceinline__ float ldin(const void* p, int idx, bool bf) {
  return bf ? bf2f(((const ushort_t*)p)[idx]) : ((const float*)p)[idx];
}
__device__ __forceinline__ bool detect_bf16(const void* xv) {
  const ushort_t* us = (const ushort_t*)xv;
  unsigned u = us[threadIdx.x & 63];
  int e = (u >> 7) & 0xFF;
  bool good = (e >= 110) && (e <= 133);
  unsigned long long m = __ballot(good);
  return __builtin_popcountll(m) >= 52;
}
__device__ __forceinline__ uint4 pack8f(const float* p) {
  float4 a = *(const float4*)p, b = *(const float4*)(p + 4);
  uint4 r;
  r.x = pk(a.x, a.y); r.y = pk(a.z, a.w);
  r.z = pk(b.x, b.y); r.w = pk(b.z, b.w);
  return r;
}

// ---------------------------------------------------------------------------
// Prep (fused): blocks 0..255 = featT (feat -> Ft[b*2048+n][64] bf16),
//               blocks 256..511 = wconv (conv_w -> bf16 Wc).
// ---------------------------------------------------------------------------
__global__ __launch_bounds__(256) void paiconv_prep(
    const void* __restrict__ xprobe, const void* __restrict__ feat,
    ushort_t* __restrict__ Ft, const void* __restrict__ W,
    ushort_t* __restrict__ Wc)
{
  const bool bfm = detect_bf16(xprobe);
  const int t = threadIdx.x;
  __shared__ ushort_t tile[64 * 72];

  if (blockIdx.x >= 256) {
    int i = ((blockIdx.x - 256) * 256 + t) << 3;
    if (bfm) *(uint4*)(Wc + i) = *(const uint4*)((const ushort_t*)W + i);
    else     *(uint4*)(Wc + i) = pack8f((const float*)W + i);
    return;
  }

  const int bb = blockIdx.x >> 5;
  const int n0 = (blockIdx.x & 31) << 6;
  {
    const int c = t & 63, ng = t >> 6;
    size_t base = (((size_t)(bb * 64 + c)) << 11) + n0 + (ng << 4);
    ushort_t v[16];
    if (bfm) {
      const ushort_t* fp_ = (const ushort_t*)feat + base;
      uint4 a = *(const uint4*)fp_, b2 = *(const uint4*)(fp_ + 8);
      unsigned uu[8] = {a.x, a.y, a.z, a.w, b2.x, b2.y, b2.z, b2.w};
#pragma unroll
      for (int e = 0; e < 8; ++e) {
        v[2 * e] = (ushort_t)(uu[e] & 0xffff);
        v[2 * e + 1] = (ushort_t)(uu[e] >> 16);
      }
    } else {
      const float* fp_ = (const float*)feat + base;
#pragma unroll
      for (int k = 0; k < 16; ++k) v[k] = f2bf(fp_[k]);
    }
#pragma unroll
    for (int k = 0; k < 16; ++k) tile[(ng * 16 + k) * 72 + c] = v[k];
  }
  __syncthreads();
  {
    const int nn = t >> 2, qtr = t & 3;
    uint4 w0 = *(const uint4*)(tile + nn * 72 + qtr * 16);
    uint4 w1 = *(const uint4*)(tile + nn * 72 + qtr * 16 + 8);
    ushort_t* dst = Ft + (((size_t)(bb * 2048 + n0 + nn)) << 6) + (qtr << 4);
    *(uint4*)dst = w0;
    *(uint4*)(dst + 8) = w1;
  }
}

// ---------------------------------------------------------------------------
// Phase 1: 2 points/block. MFMA for mlp and feats@perm. A[p][4096] bf16.
// (unchanged — verified)
// ---------------------------------------------------------------------------
__global__ __launch_bounds__(256) void paiconv_phase1(
    const void* __restrict__ x,       // [8,3,2048]
    const ushort_t* __restrict__ Ft,  // [16384][64] bf16
    const int*  __restrict__ nbr,     // [8,2048,32]
    const void* __restrict__ Brff,    // [7,32]
    const void* __restrict__ kern,    // [3,32]
    const void* __restrict__ mlpw,    // [64,64]
    const void* __restrict__ mlpb,    // [64]
    ushort_t*   __restrict__ Ag)      // [16384,4096] bf16
{
  const bool bfm = detect_bf16(x);
  const int t = threadIdx.x;
  const int p0 = blockIdx.x << 1;
  const int b  = p0 >> 11;
  const int w = t >> 6, lane = t & 63, lrow = lane & 15, quad = lane >> 4;

  __shared__ ushort_t sRt[64 * 72];
  __shared__ ushort_t sF[2 * 128 * 40];
  __shared__ ushort_t sU[64 * 72];
  __shared__ float sRel[2][32][3];
  __shared__ float sDis[2][32];
  __shared__ float sRep[2][3];
  __shared__ float sBr[224];
  __shared__ float sKn[96];
  __shared__ float sMb[64];

  const int gpt = t >> 7, gj = (t >> 2) & 31, gch = t & 3;
  const int gidx = nbr[((p0 + gpt) << 5) + gj];
  const ushort_t* gfr = Ft + (((size_t)(b * 2048 + gidx)) << 6) + (gch << 4);
  uint4 g0 = ((const uint4*)gfr)[0];
  uint4 g1 = ((const uint4*)gfr)[1];

  if (t < 224) sBr[t] = ldin(Brff, t, bfm);
  if (t < 96)  sKn[t] = ldin(kern, t, bfm);
  if (t < 64)  sMb[t] = ldin(mlpb, t, bfm);
  {
    int c = t >> 2, q0 = (t & 3) << 4;
    uint4 w0, w1;
    if (bfm) {
      const ushort_t* mp = (const ushort_t*)mlpw + c * 64 + q0;
      w0 = *(const uint4*)mp; w1 = *(const uint4*)(mp + 8);
    } else {
      const float* mp = (const float*)mlpw + c * 64 + q0;
      w0 = pack8f(mp); w1 = pack8f(mp + 8);
    }
    *(uint4*)(sU + c * 72 + q0) = w0;
    *(uint4*)(sU + c * 72 + q0 + 8) = w1;
  }
  if (t < 64) {
    int pt = t >> 5, i = t & 31;
    int p = p0 + pt;
    int idx  = nbr[(p << 5) + i];
    int idx0 = nbr[(p << 5)];
    int xo = b * 6144;
    float rx = ldin(x, xo + idx0, bfm);
    float ry = ldin(x, xo + 2048 + idx0, bfm);
    float rz = ldin(x, xo + 4096 + idx0, bfm);
    float cx = ldin(x, xo + idx, bfm);
    float cy = ldin(x, xo + 2048 + idx, bfm);
    float cz = ldin(x, xo + 4096 + idx, bfm);
    float dx = cx - rx, dy = cy - ry, dz = cz - rz;
    sRel[pt][i][0] = dx; sRel[pt][i][1] = dy; sRel[pt][i][2] = dz;
    sDis[pt][i] = sqrtf(dx * dx + dy * dy + dz * dz);
    if (i == 0) { sRep[pt][0] = rx; sRep[pt][1] = ry; sRep[pt][2] = rz; }
  }
  __syncthreads();   // b1

  {
    int jn = t >> 2, mh = (t & 3) << 3;
    int pt = jn >> 5, j = jn & 31;
    float pos[7];
    pos[0] = TWO_PI * sRep[pt][0]; pos[1] = TWO_PI * sRep[pt][1];
    pos[2] = TWO_PI * sRep[pt][2];
    pos[3] = TWO_PI * sRel[pt][j][0]; pos[4] = TWO_PI * sRel[pt][j][1];
    pos[5] = TWO_PI * sRel[pt][j][2];
    pos[6] = TWO_PI * sDis[pt][j];
    unsigned sw[4], cw[4];
#pragma unroll
    for (int mm = 0; mm < 8; mm += 2) {
      float a0 = 0.f, a1 = 0.f;
#pragma unroll
      for (int d = 0; d < 7; ++d) {
        a0 += pos[d] * sBr[d * 32 + mh + mm];
        a1 += pos[d] * sBr[d * 32 + mh + mm + 1];
      }
      sw[mm >> 1] = pk(__sinf(a0), __sinf(a1));
      cw[mm >> 1] = pk(__cosf(a0), __cosf(a1));
    }
    ushort_t* rb = sRt + jn * 72;
    *(uint4*)(rb + mh)      = make_uint4(sw[0], sw[1], sw[2], sw[3]);
    *(uint4*)(rb + 32 + mh) = make_uint4(cw[0], cw[1], cw[2], cw[3]);
  }
  __syncthreads();   // b2

  {
    int c = (w << 4) + lrow;
    int row = (c & 31) * 4 + 2 + (c >> 5);
    float bv = sMb[c];
    short8 b0 = *(const short8*)(sU + c * 72 + (quad << 3));
    short8 b1 = *(const short8*)(sU + c * 72 + 32 + (quad << 3));
#pragma unroll
    for (int mt = 0; mt < 4; ++mt) {
      const ushort_t* rp = sRt + (mt * 16 + lrow) * 72 + (quad << 3);
      short8 a0 = *(const short8*)rp;
      short8 a1 = *(const short8*)(rp + 32);
      floatx4 acc = {0.f, 0.f, 0.f, 0.f};
      acc = __builtin_amdgcn_mfma_f32_16x16x32_bf16(a0, b0, acc, 0, 0, 0);
      acc = __builtin_amdgcn_mfma_f32_16x16x32_bf16(a1, b1, acc, 0, 0, 0);
      int pt = mt >> 1;
      int j0 = ((mt & 1) << 4) + (quad << 2);
      *(uint2*)(sF + pt * 5120 + row * 40 + j0) =
          make_uint2(pk(acc[0] + bv, acc[1] + bv), pk(acc[2] + bv, acc[3] + bv));
    }
  }
  {
    ushort_t* fp_ = sF + gpt * 5120 + (gch >> 1) * 40 + (gch & 1) * 2560 + gj;
    unsigned uu[8] = {g0.x, g0.y, g0.z, g0.w, g1.x, g1.y, g1.z, g1.w};
#pragma unroll
    for (int u = 0; u < 8; ++u) {
      fp_[(2 * u) * 160]     = (ushort_t)(uu[u] & 0xffff);
      fp_[(2 * u + 1) * 160] = (ushort_t)(uu[u] >> 16);
    }
  }
  __syncthreads();   // b3

  if (t < 64) {
    int pt = t >> 5, j = t & 31;
    float k0 = sKn[j], k1 = sKn[32 + j], k2 = sKn[64 + j];
    float col[32];
    float s1 = 0.f;
#pragma unroll
    for (int i = 0; i < 32; ++i) {
      float v = sRel[pt][i][0] * k0 + sRel[pt][i][1] * k1 + sRel[pt][i][2] * k2;
      if (i == 0 && j == 0) v += 1.0f;
      v = fmaxf(v, 0.f);
      col[i] = v; s1 += v;
    }
    float inv1 = 1.0f / (s1 + 1e-6f);
    float s2 = 0.f;
#pragma unroll
    for (int i = 0; i < 32; ++i) { float v = col[i] * inv1; v = v * v; col[i] = v; s2 += v; }
    float inv2 = 1.0f / (s2 + 1e-6f);
    unsigned pw[16];
#pragma unroll
    for (int i = 0; i < 32; i += 2) {
      float v0 = col[i] * inv2;     v0 = (v0 > 0.1f) ? v0 : 0.f;
      float v1 = col[i + 1] * inv2; v1 = (v1 > 0.1f) ? v1 : 0.f;
      pw[i >> 1] = pk(v0, v1);
    }
    ushort_t* dst = sU + pt * 1280 + j * 40;
#pragma unroll
    for (int g = 0; g < 4; ++g)
      *(uint4*)(dst + g * 8) = make_uint4(pw[4 * g], pw[4 * g + 1], pw[4 * g + 2], pw[4 * g + 3]);
  }
  __syncthreads();   // b4

  {
#pragma unroll
    for (int pt = 0; pt < 2; ++pt) {
      const ushort_t* Pp = sU + pt * 1280;
      short8 a0 = *(const short8*)(Pp + lrow * 40 + (quad << 3));
      short8 a1 = *(const short8*)(Pp + (16 + lrow) * 40 + (quad << 3));
      size_t prow = ((size_t)(p0 + pt)) << 12;
#pragma unroll
      for (int nt = 0; nt < 2; ++nt) {
        int cidx = ((w * 2 + nt) << 4) + lrow;
        short8 bfg = *(const short8*)(sF + pt * 5120 + cidx * 40 + (quad << 3));
        floatx4 z = {0.f, 0.f, 0.f, 0.f};
        floatx4 c0 = __builtin_amdgcn_mfma_f32_16x16x32_bf16(a0, bfg, z, 0, 0, 0);
        floatx4 c1 = __builtin_amdgcn_mfma_f32_16x16x32_bf16(a1, bfg, z, 0, 0, 0);
        ushort_t* ad = Ag + prow + cidx * 32 + (quad << 2);
        *(uint2*)ad        = make_uint2(pk(c0[0], c0[1]), pk(c0[2], c0[3]));
        *(uint2*)(ad + 16) = make_uint2(pk(c1[0], c1[1]), pk(c1[2], c1[3]));
      }
    }
  }
}

// ---------------------------------------------------------------------------
// Phase 2: bf16 MFMA GEMM, BM=64 BN=128 BK=64, split-K=2, grid (256,2).
// LDS double-buffered: ONE barrier per K-iter; register prefetch 1 iter deep.
// ---------------------------------------------------------------------------
__global__ __launch_bounds__(256) void paiconv_gemm(
    const ushort_t* __restrict__ A,    // [16384,4096] bf16
    const ushort_t* __restrict__ Wc,   // [128,4096] bf16
    float* __restrict__ part)          // [2][16384][128] fp32
{
  __shared__ ushort_t lA[2][64 * 72];   // 2 x 9.2 KB
  __shared__ ushort_t lB[2][128 * 72];  // 2 x 18.4 KB
  const int m0 = blockIdx.x << 6;
  const int K0 = blockIdx.y << 11;
  const int t = threadIdx.x;
  const int w = t >> 6, lane = t & 63;
  const int wm = w & 1, wn = w >> 1, lrow = lane & 15, quad = lane >> 4;

  const int ar = t >> 2, ac = (t & 3) << 4;   // A: 64 rows x 64k, 16 elems/thr
  const int wr = t >> 1, wc = (t & 1) << 5;   // W: 128 rows x 64k, 32 elems/thr
  const ushort_t* Ap = A + (size_t)(m0 + ar) * 4096 + K0 + ac;
  const ushort_t* Wp = Wc + (size_t)wr * 4096 + K0 + wc;

  uint4 ra0 = *(const uint4*)Ap, ra1 = *(const uint4*)(Ap + 8);
  uint4 rb0 = *(const uint4*)Wp, rb1 = *(const uint4*)(Wp + 8);
  uint4 rb2 = *(const uint4*)(Wp + 16), rb3 = *(const uint4*)(Wp + 24);

  floatx4 acc[2][4];
#pragma unroll
  for (int i = 0; i < 2; ++i)
#pragma unroll
    for (int j = 0; j < 4; ++j) acc[i][j] = (floatx4){0.f, 0.f, 0.f, 0.f};

  for (int kb = 0; kb < 32; ++kb) {
    // prefetch next slice (independent of pending LDS writes)
    uint4 na0, na1, nb0, nb1, nb2, nb3;
    if (kb < 31) {
      int off = (kb + 1) << 6;
      na0 = *(const uint4*)(Ap + off);      na1 = *(const uint4*)(Ap + off + 8);
      nb0 = *(const uint4*)(Wp + off);      nb1 = *(const uint4*)(Wp + off + 8);
      nb2 = *(const uint4*)(Wp + off + 16); nb3 = *(const uint4*)(Wp + off + 24);
    }
    ushort_t* la = lA[kb & 1];
    ushort_t* lb = lB[kb & 1];
    *(uint4*)(la + ar * 72 + ac)      = ra0;
    *(uint4*)(la + ar * 72 + ac + 8)  = ra1;
    *(uint4*)(lb + wr * 72 + wc)      = rb0;
    *(uint4*)(lb + wr * 72 + wc + 8)  = rb1;
    *(uint4*)(lb + wr * 72 + wc + 16) = rb2;
    *(uint4*)(lb + wr * 72 + wc + 24) = rb3;
    __syncthreads();   // single barrier per iter (dbuf makes 2nd unnecessary)

#pragma unroll
    for (int kk = 0; kk < 2; ++kk) {
      short8 af0 = *(const short8*)(la + ((wm << 5) + lrow) * 72 + (kk << 5) + (quad << 3));
      short8 af1 = *(const short8*)(la + ((wm << 5) + 16 + lrow) * 72 + (kk << 5) + (quad << 3));
#pragma unroll
      for (int ni = 0; ni < 4; ++ni) {
        short8 bf = *(const short8*)(lb + ((wn << 6) + (ni << 4) + lrow) * 72 +
                                     (kk << 5) + (quad << 3));
        acc[0][ni] = __builtin_amdgcn_mfma_f32_16x16x32_bf16(af0, bf, acc[0][ni], 0, 0, 0);
        acc[1][ni] = __builtin_amdgcn_mfma_f32_16x16x32_bf16(af1, bf, acc[1][ni], 0, 0, 0);
      }
    }
    ra0 = na0; ra1 = na1;
    rb0 = nb0; rb1 = nb1; rb2 = nb2; rb3 = nb3;
  }

  float* dst = part + ((size_t)blockIdx.y << 21);
#pragma unroll
  for (int mi = 0; mi < 2; ++mi)
#pragma unroll
    for (int ni = 0; ni < 4; ++ni)
#pragma unroll
      for (int r = 0; r < 4; ++r) {
        int m = m0 + (wm << 5) + (mi << 4) + (quad << 2) + r;
        int n = (wn << 6) + (ni << 4) + lrow;
        dst[(size_t)m * 128 + n] = acc[mi][ni][r];
      }
}

// ---------------------------------------------------------------------------
// Reduce: sum 2 split-K partials + bias, transpose to out[B,C,N].
// ---------------------------------------------------------------------------
__global__ __launch_bounds__(256) void paiconv_reduce(
    const void* __restrict__ xprobe, const float* __restrict__ part,
    const void* __restrict__ bias, void* __restrict__ out)
{
  const bool bfm = detect_bf16(xprobe);
  __shared__ float buf[128 * 65];
  const int m0 = blockIdx.x << 6;
  const int b = m0 >> 11, n0 = m0 & 2047;
  const int t = threadIdx.x;

#pragma unroll 4
  for (int i = 0; i < 32; ++i) {
    int idx = i * 256 + t;
    int mt = idx >> 7, c = idx & 127;
    size_t o = (size_t)(m0 + mt) * 128 + c;
    float s = ldin(bias, c, bfm) + part[o] + part[(1u << 21) + o];
    buf[c * 65 + mt] = s;
  }
  __syncthreads();
#pragma unroll 4
  for (int i = 0; i < 32; ++i) {
    int idx = i * 256 + t;
    int c = idx >> 6, nl = idx & 63;
    float v = buf[c * 65 + nl];
    size_t o = (size_t)b * 262144 + (size_t)c * 2048 + n0 + nl;
    if (bfm) ((ushort_t*)out)[o] = f2bf(v);
    else     ((float*)out)[o] = v;
  }
}

extern "C" void kernel_launch(void* const* d_in, const int* in_sizes, int n_in,
                              void* d_out, int out_size, void* d_ws, size_t ws_size,
                              hipStream_t stream) {
  const void* x     = d_in[0];
  const void* feat  = d_in[1];
  const int*  nbr   = (const int*)d_in[2];
  const void* Brff  = d_in[3];
  const void* kern  = d_in[4];
  const void* mlpw  = d_in[5];
  const void* mlpb  = d_in[6];
  const void* convw = d_in[7];
  const void* convb = d_in[8];

  char* ws = (char*)d_ws;
  ushort_t* A   = (ushort_t*)ws;                          // 128 MiB
  ushort_t* Wcv = (ushort_t*)(ws + (size_t)134217728);    // 1 MiB
  float*    prt = (float*)(ws + (size_t)135266304);       // 16 MiB
  ushort_t* Ft  = (ushort_t*)(ws + (size_t)152043520);    // 2 MiB

  paiconv_prep<<<512, 256, 0, stream>>>(x, feat, Ft, convw, Wcv);
  paiconv_phase1<<<8192, 256, 0, stream>>>(x, Ft, nbr, Brff, kern, mlpw, mlpb, A);
  paiconv_gemm<<<dim3(256, 2, 1), 256, 0, stream>>>(A, Wcv, prt);
  paiconv_reduce<<<256, 256, 0, stream>>>(x, prt, convb, d_out);
}

// Round 9
// 182.116 us; speedup vs baseline: 1.3089x; 1.0510x over previous
//
#include <hip/hip_runtime.h>

typedef unsigned short ushort_t;
typedef __attribute__((ext_vector_type(8))) short short8;
typedef __attribute__((ext_vector_type(4))) float floatx4;

#define TWO_PI 6.28318530717958647692f

__device__ __forceinline__ float bf2f(ushort_t u) {
  union { unsigned u; float f; } v; v.u = ((unsigned)u) << 16; return v.f;
}
__device__ __forceinline__ ushort_t f2bf(float f) {
  union { float f; unsigned u; } v; v.f = f;
  unsigned r = v.u + 0x7FFFu + ((v.u >> 16) & 1u);
  return (ushort_t)(r >> 16);
}
__device__ __forceinline__ unsigned pk(float a, float b) {
  return (unsigned)f2bf(a) | ((unsigned)f2bf(b) << 16);
}
__device__ __forceinline__ float ldin(const void* p, int idx, bool bf) {
  return bf ? bf2f(((const ushort_t*)p)[idx]) : ((const float*)p)[idx];
}
__device__ __forceinline__ bool detect_bf16(const void* xv) {
  const ushort_t* us = (const ushort_t*)xv;
  unsigned u = us[threadIdx.x & 63];
  int e = (u >> 7) & 0xFF;
  bool good = (e >= 110) && (e <= 133);
  unsigned long long m = __ballot(good);
  return __builtin_popcountll(m) >= 52;
}
__device__ __forceinline__ uint4 pack8f(const float* p) {
  float4 a = *(const float4*)p, b = *(const float4*)(p + 4);
  uint4 r;
  r.x = pk(a.x, a.y); r.y = pk(a.z, a.w);
  r.z = pk(b.x, b.y); r.w = pk(b.z, b.w);
  return r;
}

// ---------------------------------------------------------------------------
// Prep (fused): blocks 0..255 = featT (feat -> Ft[b*2048+n][64] bf16),
//               blocks 256..511 = wconv (conv_w -> bf16 Wc).
// ---------------------------------------------------------------------------
__global__ __launch_bounds__(256) void paiconv_prep(
    const void* __restrict__ xprobe, const void* __restrict__ feat,
    ushort_t* __restrict__ Ft, const void* __restrict__ W,
    ushort_t* __restrict__ Wc)
{
  const bool bfm = detect_bf16(xprobe);
  const int t = threadIdx.x;
  __shared__ ushort_t tile[64 * 72];

  if (blockIdx.x >= 256) {
    int i = ((blockIdx.x - 256) * 256 + t) << 3;
    if (bfm) *(uint4*)(Wc + i) = *(const uint4*)((const ushort_t*)W + i);
    else     *(uint4*)(Wc + i) = pack8f((const float*)W + i);
    return;
  }

  const int bb = blockIdx.x >> 5;
  const int n0 = (blockIdx.x & 31) << 6;
  {
    const int c = t & 63, ng = t >> 6;
    size_t base = (((size_t)(bb * 64 + c)) << 11) + n0 + (ng << 4);
    ushort_t v[16];
    if (bfm) {
      const ushort_t* fp_ = (const ushort_t*)feat + base;
      uint4 a = *(const uint4*)fp_, b2 = *(const uint4*)(fp_ + 8);
      unsigned uu[8] = {a.x, a.y, a.z, a.w, b2.x, b2.y, b2.z, b2.w};
#pragma unroll
      for (int e = 0; e < 8; ++e) {
        v[2 * e] = (ushort_t)(uu[e] & 0xffff);
        v[2 * e + 1] = (ushort_t)(uu[e] >> 16);
      }
    } else {
      const float* fp_ = (const float*)feat + base;
#pragma unroll
      for (int k = 0; k < 16; ++k) v[k] = f2bf(fp_[k]);
    }
#pragma unroll
    for (int k = 0; k < 16; ++k) tile[(ng * 16 + k) * 72 + c] = v[k];
  }
  __syncthreads();
  {
    const int nn = t >> 2, qtr = t & 3;
    uint4 w0 = *(const uint4*)(tile + nn * 72 + qtr * 16);
    uint4 w1 = *(const uint4*)(tile + nn * 72 + qtr * 16 + 8);
    ushort_t* dst = Ft + (((size_t)(bb * 2048 + n0 + nn)) << 6) + (qtr << 4);
    *(uint4*)dst = w0;
    *(uint4*)(dst + 8) = w1;
  }
}

// ---------------------------------------------------------------------------
// Phase 1: 2 points/block, 3 barriers, ~37.4 KB LDS -> 4 blocks/CU.
// mlpw fragments come straight from global (no LDS stage); P^T has its own
// buffer so perm build shares the barrier interval with the RFF build.
// ---------------------------------------------------------------------------
__global__ __launch_bounds__(256) void paiconv_phase1(
    const void* __restrict__ x,       // [8,3,2048]
    const ushort_t* __restrict__ Ft,  // [16384][64] bf16
    const int*  __restrict__ nbr,     // [8,2048,32]
    const void* __restrict__ Brff,    // [7,32]
    const void* __restrict__ kern,    // [3,32]
    const void* __restrict__ mlpw,    // [64,64]
    const void* __restrict__ mlpb,    // [64]
    ushort_t*   __restrict__ Ag)      // [16384,4096] bf16
{
  const bool bfm = detect_bf16(x);
  const int t = threadIdx.x;
  const int p0 = blockIdx.x << 1;
  const int b  = p0 >> 11;
  const int w = t >> 6, lane = t & 63, lrow = lane & 15, quad = lane >> 4;

  __shared__ ushort_t sRt[64 * 72];     // 9.2 KB
  __shared__ ushort_t sF[2 * 128 * 40]; // 20.5 KB
  __shared__ ushort_t sP[2 * 32 * 40];  // 5.1 KB (P^T)
  __shared__ float sRel[2][32][3];
  __shared__ float sDis[2][32];
  __shared__ float sRep[2][3];
  __shared__ float sBr[224];
  __shared__ float sKn[96];
  __shared__ float sMb[64];

  // ---- gather prefetch: 16 channels (2 uint4) per thread, issued first ----
  const int gpt = t >> 7, gj = (t >> 2) & 31, gch = t & 3;
  const int gidx = nbr[((p0 + gpt) << 5) + gj];
  const ushort_t* gfr = Ft + (((size_t)(b * 2048 + gidx)) << 6) + (gch << 4);
  uint4 g0 = ((const uint4*)gfr)[0];
  uint4 g1 = ((const uint4*)gfr)[1];

  // ---- mlpw fragments direct from global (row c, 16B per quad) ----
  const int mc = (w << 4) + lrow;       // this thread's mlp output channel
  short8 mb0, mb1;
  if (bfm) {
    const ushort_t* mp = (const ushort_t*)mlpw + mc * 64;
    mb0 = *(const short8*)(mp + (quad << 3));
    mb1 = *(const short8*)(mp + 32 + (quad << 3));
  } else {
    const float* mp = (const float*)mlpw + mc * 64;
    uint4 u0 = pack8f(mp + (quad << 3));
    uint4 u1 = pack8f(mp + 32 + (quad << 3));
    mb0 = *(short8*)&u0;
    mb1 = *(short8*)&u1;
  }

  // ---- constants to LDS ----
  if (t < 224) sBr[t] = ldin(Brff, t, bfm);
  if (t < 96)  sKn[t] = ldin(kern, t, bfm);
  if (t < 64)  sMb[t] = ldin(mlpb, t, bfm);
  // ---- neighbor geometry ----
  if (t < 64) {
    int pt = t >> 5, i = t & 31;
    int p = p0 + pt;
    int idx  = nbr[(p << 5) + i];
    int idx0 = nbr[(p << 5)];
    int xo = b * 6144;
    float rx = ldin(x, xo + idx0, bfm);
    float ry = ldin(x, xo + 2048 + idx0, bfm);
    float rz = ldin(x, xo + 4096 + idx0, bfm);
    float cx = ldin(x, xo + idx, bfm);
    float cy = ldin(x, xo + 2048 + idx, bfm);
    float cz = ldin(x, xo + 4096 + idx, bfm);
    float dx = cx - rx, dy = cy - ry, dz = cz - rz;
    sRel[pt][i][0] = dx; sRel[pt][i][1] = dy; sRel[pt][i][2] = dz;
    sDis[pt][i] = sqrtf(dx * dx + dy * dy + dz * dz);
    if (i == 0) { sRep[pt][0] = rx; sRep[pt][1] = ry; sRep[pt][2] = rz; }
  }
  __syncthreads();   // b1

  // ---- step 2: R^T build (8 m's per thread) ----
  {
    int jn = t >> 2, mh = (t & 3) << 3;
    int pt = jn >> 5, j = jn & 31;
    float pos[7];
    pos[0] = TWO_PI * sRep[pt][0]; pos[1] = TWO_PI * sRep[pt][1];
    pos[2] = TWO_PI * sRep[pt][2];
    pos[3] = TWO_PI * sRel[pt][j][0]; pos[4] = TWO_PI * sRel[pt][j][1];
    pos[5] = TWO_PI * sRel[pt][j][2];
    pos[6] = TWO_PI * sDis[pt][j];
    unsigned sw[4], cw[4];
#pragma unroll
    for (int mm = 0; mm < 8; mm += 2) {
      float a0 = 0.f, a1 = 0.f;
#pragma unroll
      for (int d = 0; d < 7; ++d) {
        a0 += pos[d] * sBr[d * 32 + mh + mm];
        a1 += pos[d] * sBr[d * 32 + mh + mm + 1];
      }
      sw[mm >> 1] = pk(__sinf(a0), __sinf(a1));
      cw[mm >> 1] = pk(__cosf(a0), __cosf(a1));
    }
    ushort_t* rb = sRt + jn * 72;
    *(uint4*)(rb + mh)      = make_uint4(sw[0], sw[1], sw[2], sw[3]);
    *(uint4*)(rb + 32 + mh) = make_uint4(cw[0], cw[1], cw[2], cw[3]);
  }

  // ---- step 5 (moved up): perm build -> P^T in sP (needs only sRel/sKn) ----
  if (t < 64) {
    int pt = t >> 5, j = t & 31;
    float k0 = sKn[j], k1 = sKn[32 + j], k2 = sKn[64 + j];
    float col[32];
    float s1 = 0.f;
#pragma unroll
    for (int i = 0; i < 32; ++i) {
      float v = sRel[pt][i][0] * k0 + sRel[pt][i][1] * k1 + sRel[pt][i][2] * k2;
      if (i == 0 && j == 0) v += 1.0f;
      v = fmaxf(v, 0.f);
      col[i] = v; s1 += v;
    }
    float inv1 = 1.0f / (s1 + 1e-6f);
    float s2 = 0.f;
#pragma unroll
    for (int i = 0; i < 32; ++i) { float v = col[i] * inv1; v = v * v; col[i] = v; s2 += v; }
    float inv2 = 1.0f / (s2 + 1e-6f);
    unsigned pw[16];
#pragma unroll
    for (int i = 0; i < 32; i += 2) {
      float v0 = col[i] * inv2;     v0 = (v0 > 0.1f) ? v0 : 0.f;
      float v1 = col[i + 1] * inv2; v1 = (v1 > 0.1f) ? v1 : 0.f;
      pw[i >> 1] = pk(v0, v1);
    }
    ushort_t* dst = sP + pt * 1280 + j * 40;
#pragma unroll
    for (int g = 0; g < 4; ++g)
      *(uint4*)(dst + g * 8) = make_uint4(pw[4 * g], pw[4 * g + 1], pw[4 * g + 2], pw[4 * g + 3]);
  }
  __syncthreads();   // b2 (sRt + sP ready)

  // ---- step 3: mlp MFMA -> sF rows 2,3 mod 4 ----
  {
    int row = (mc & 31) * 4 + 2 + (mc >> 5);
    float bv = sMb[mc];
#pragma unroll
    for (int mt = 0; mt < 4; ++mt) {
      const ushort_t* rp = sRt + (mt * 16 + lrow) * 72 + (quad << 3);
      short8 a0 = *(const short8*)rp;
      short8 a1 = *(const short8*)(rp + 32);
      floatx4 acc = {0.f, 0.f, 0.f, 0.f};
      acc = __builtin_amdgcn_mfma_f32_16x16x32_bf16(a0, mb0, acc, 0, 0, 0);
      acc = __builtin_amdgcn_mfma_f32_16x16x32_bf16(a1, mb1, acc, 0, 0, 0);
      int pt = mt >> 1;
      int j0 = ((mt & 1) << 4) + (quad << 2);
      *(uint2*)(sF + pt * 5120 + row * 40 + j0) =
          make_uint2(pk(acc[0] + bv, acc[1] + bv), pk(acc[2] + bv, acc[3] + bv));
    }
  }
  // ---- step 4: gather regs -> sF rows 0,1 mod 4 ----
  {
    ushort_t* fp_ = sF + gpt * 5120 + (gch >> 1) * 40 + (gch & 1) * 2560 + gj;
    unsigned uu[8] = {g0.x, g0.y, g0.z, g0.w, g1.x, g1.y, g1.z, g1.w};
#pragma unroll
    for (int u = 0; u < 8; ++u) {
      fp_[(2 * u) * 160]     = (ushort_t)(uu[u] & 0xffff);
      fp_[(2 * u + 1) * 160] = (ushort_t)(uu[u] >> 16);
    }
  }
  __syncthreads();   // b3 (sF ready)

  // ---- step 6: F@P via MFMA -> global A ----
  {
#pragma unroll
    for (int pt = 0; pt < 2; ++pt) {
      const ushort_t* Pp = sP + pt * 1280;
      short8 a0 = *(const short8*)(Pp + lrow * 40 + (quad << 3));
      short8 a1 = *(const short8*)(Pp + (16 + lrow) * 40 + (quad << 3));
      size_t prow = ((size_t)(p0 + pt)) << 12;
#pragma unroll
      for (int nt = 0; nt < 2; ++nt) {
        int cidx = ((w * 2 + nt) << 4) + lrow;
        short8 bfg = *(const short8*)(sF + pt * 5120 + cidx * 40 + (quad << 3));
        floatx4 z = {0.f, 0.f, 0.f, 0.f};
        floatx4 c0 = __builtin_amdgcn_mfma_f32_16x16x32_bf16(a0, bfg, z, 0, 0, 0);
        floatx4 c1 = __builtin_amdgcn_mfma_f32_16x16x32_bf16(a1, bfg, z, 0, 0, 0);
        ushort_t* ad = Ag + prow + cidx * 32 + (quad << 2);
        *(uint2*)ad        = make_uint2(pk(c0[0], c0[1]), pk(c0[2], c0[3]));
        *(uint2*)(ad + 16) = make_uint2(pk(c1[0], c1[1]), pk(c1[2], c1[3]));
      }
    }
  }
}

// ---------------------------------------------------------------------------
// Phase 2: bf16 MFMA GEMM, BM=64 BN=128 BK=64, split-K=2, grid (256,2).
// LDS double-buffered: ONE barrier per K-iter; register prefetch 1 iter deep.
// (unchanged from round 8 — best so far)
// ---------------------------------------------------------------------------
__global__ __launch_bounds__(256) void paiconv_gemm(
    const ushort_t* __restrict__ A,    // [16384,4096] bf16
    const ushort_t* __restrict__ Wc,   // [128,4096] bf16
    float* __restrict__ part)          // [2][16384][128] fp32
{
  __shared__ ushort_t lA[2][64 * 72];
  __shared__ ushort_t lB[2][128 * 72];
  const int m0 = blockIdx.x << 6;
  const int K0 = blockIdx.y << 11;
  const int t = threadIdx.x;
  const int w = t >> 6, lane = t & 63;
  const int wm = w & 1, wn = w >> 1, lrow = lane & 15, quad = lane >> 4;

  const int ar = t >> 2, ac = (t & 3) << 4;
  const int wr = t >> 1, wc = (t & 1) << 5;
  const ushort_t* Ap = A + (size_t)(m0 + ar) * 4096 + K0 + ac;
  const ushort_t* Wp = Wc + (size_t)wr * 4096 + K0 + wc;

  uint4 ra0 = *(const uint4*)Ap, ra1 = *(const uint4*)(Ap + 8);
  uint4 rb0 = *(const uint4*)Wp, rb1 = *(const uint4*)(Wp + 8);
  uint4 rb2 = *(const uint4*)(Wp + 16), rb3 = *(const uint4*)(Wp + 24);

  floatx4 acc[2][4];
#pragma unroll
  for (int i = 0; i < 2; ++i)
#pragma unroll
    for (int j = 0; j < 4; ++j) acc[i][j] = (floatx4){0.f, 0.f, 0.f, 0.f};

  for (int kb = 0; kb < 32; ++kb) {
    uint4 na0, na1, nb0, nb1, nb2, nb3;
    if (kb < 31) {
      int off = (kb + 1) << 6;
      na0 = *(const uint4*)(Ap + off);      na1 = *(const uint4*)(Ap + off + 8);
      nb0 = *(const uint4*)(Wp + off);      nb1 = *(const uint4*)(Wp + off + 8);
      nb2 = *(const uint4*)(Wp + off + 16); nb3 = *(const uint4*)(Wp + off + 24);
    }
    ushort_t* la = lA[kb & 1];
    ushort_t* lb = lB[kb & 1];
    *(uint4*)(la + ar * 72 + ac)      = ra0;
    *(uint4*)(la + ar * 72 + ac + 8)  = ra1;
    *(uint4*)(lb + wr * 72 + wc)      = rb0;
    *(uint4*)(lb + wr * 72 + wc + 8)  = rb1;
    *(uint4*)(lb + wr * 72 + wc + 16) = rb2;
    *(uint4*)(lb + wr * 72 + wc + 24) = rb3;
    __syncthreads();

#pragma unroll
    for (int kk = 0; kk < 2; ++kk) {
      short8 af0 = *(const short8*)(la + ((wm << 5) + lrow) * 72 + (kk << 5) + (quad << 3));
      short8 af1 = *(const short8*)(la + ((wm << 5) + 16 + lrow) * 72 + (kk << 5) + (quad << 3));
#pragma unroll
      for (int ni = 0; ni < 4; ++ni) {
        short8 bf = *(const short8*)(lb + ((wn << 6) + (ni << 4) + lrow) * 72 +
                                     (kk << 5) + (quad << 3));
        acc[0][ni] = __builtin_amdgcn_mfma_f32_16x16x32_bf16(af0, bf, acc[0][ni], 0, 0, 0);
        acc[1][ni] = __builtin_amdgcn_mfma_f32_16x16x32_bf16(af1, bf, acc[1][ni], 0, 0, 0);
      }
    }
    ra0 = na0; ra1 = na1;
    rb0 = nb0; rb1 = nb1; rb2 = nb2; rb3 = nb3;
  }

  float* dst = part + ((size_t)blockIdx.y << 21);
#pragma unroll
  for (int mi = 0; mi < 2; ++mi)
#pragma unroll
    for (int ni = 0; ni < 4; ++ni)
#pragma unroll
      for (int r = 0; r < 4; ++r) {
        int m = m0 + (wm << 5) + (mi << 4) + (quad << 2) + r;
        int n = (wn << 6) + (ni << 4) + lrow;
        dst[(size_t)m * 128 + n] = acc[mi][ni][r];
      }
}

// ---------------------------------------------------------------------------
// Reduce: sum 2 split-K partials + bias, transpose to out[B,C,N].
// ---------------------------------------------------------------------------
__global__ __launch_bounds__(256) void paiconv_reduce(
    const void* __restrict__ xprobe, const float* __restrict__ part,
    const void* __restrict__ bias, void* __restrict__ out)
{
  const bool bfm = detect_bf16(xprobe);
  __shared__ float buf[128 * 65];
  const int m0 = blockIdx.x << 6;
  const int b = m0 >> 11, n0 = m0 & 2047;
  const int t = threadIdx.x;

#pragma unroll 4
  for (int i = 0; i < 32; ++i) {
    int idx = i * 256 + t;
    int mt = idx >> 7, c = idx & 127;
    size_t o = (size_t)(m0 + mt) * 128 + c;
    float s = ldin(bias, c, bfm) + part[o] + part[(1u << 21) + o];
    buf[c * 65 + mt] = s;
  }
  __syncthreads();
#pragma unroll 4
  for (int i = 0; i < 32; ++i) {
    int idx = i * 256 + t;
    int c = idx >> 6, nl = idx & 63;
    float v = buf[c * 65 + nl];
    size_t o = (size_t)b * 262144 + (size_t)c * 2048 + n0 + nl;
    if (bfm) ((ushort_t*)out)[o] = f2bf(v);
    else     ((float*)out)[o] = v;
  }
}

extern "C" void kernel_launch(void* const* d_in, const int* in_sizes, int n_in,
                              void* d_out, int out_size, void* d_ws, size_t ws_size,
                              hipStream_t stream) {
  const void* x     = d_in[0];
  const void* feat  = d_in[1];
  const int*  nbr   = (const int*)d_in[2];
  const void* Brff  = d_in[3];
  const void* kern  = d_in[4];
  const void* mlpw  = d_in[5];
  const void* mlpb  = d_in[6];
  const void* convw = d_in[7];
  const void* convb = d_in[8];

  char* ws = (char*)d_ws;
  ushort_t* A   = (ushort_t*)ws;                          // 128 MiB
  ushort_t* Wcv = (ushort_t*)(ws + (size_t)134217728);    // 1 MiB
  float*    prt = (float*)(ws + (size_t)135266304);       // 16 MiB
  ushort_t* Ft  = (ushort_t*)(ws + (size_t)152043520);    // 2 MiB

  paiconv_prep<<<512, 256, 0, stream>>>(x, feat, Ft, convw, Wcv);
  paiconv_phase1<<<8192, 256, 0, stream>>>(x, Ft, nbr, Brff, kern, mlpw, mlpb, A);
  paiconv_gemm<<<dim3(256, 2, 1), 256, 0, stream>>>(A, Wcv, prt);
  paiconv_reduce<<<256, 256, 0, stream>>>(x, prt, convb, d_out);
}